// Round 3
// baseline (406.244 us; speedup 1.0000x reference)
//
#include <hip/hip_runtime.h>
#include <hip/hip_bf16.h>

// DotProductAttention: B=4, N=4096, E=1024, D=256. f32 in/out.
// Pipeline: cast/prep -> QKV GEMM (z=3) -> VT GEMM -> k_score (packed
// lower-tri P~, rowsum l) -> k_pv (O = P~ @ V / l).
// R7: load-balance fixes. k_score enumerates only the 528 lower-tri tiles/b.
// R8/R9: coset-balanced k_pv (1024 blocks). FAILED to move MfmaUtil (24%):
// balance fixed the per-CU work SUM but the makespan is the longest serial
// chain (qt=31: 128 k-steps); avg concurrency stayed ~2 blocks/CU.
// R10: split-k. Every (qt,dv,b) tile is split along K into chunks of 8
// k-tiles (32 k-steps). 80 chunks per (dv,b) -> grid (80,8,4) = 2560
// near-uniform blocks, 8 resident/CU (wave cap). Partial tiles are scaled
// by 1/l (linear => exact) and combined with unsafeAtomicAdd
// (global_atomic_add_f32); qt<=7 tiles are single-chunk -> plain store.
// Out zeroed via hipMemsetAsync up front.

typedef __hip_bfloat16 bf16;
typedef __bf16 bf16x4 __attribute__((ext_vector_type(4)));
typedef __bf16 bf16x8 __attribute__((ext_vector_type(8)));
typedef float f32x4 __attribute__((ext_vector_type(4)));

#define BK 32

__device__ __forceinline__ void gload_lds16(const bf16* g, bf16* l) {
    __builtin_amdgcn_global_load_lds(
        (const __attribute__((address_space(1))) unsigned int*)g,
        (__attribute__((address_space(3))) unsigned int*)l, 16, 0, 0);
}

__device__ __forceinline__ void zero_acc(f32x4 acc[4][4]) {
#pragma unroll
    for (int mi = 0; mi < 4; ++mi)
#pragma unroll
        for (int ni = 0; ni < 4; ++ni) {
            f32x4 zf = {0.f, 0.f, 0.f, 0.f};
            acc[mi][ni] = zf;
        }
}

// C-tile accumulate: acc += A[128 x K] * BT[128 x K]^T (m97 structure).
__device__ __forceinline__ void mm_tile(const bf16* __restrict__ Ablk,
                                        const bf16* __restrict__ Bblk,
                                        int lda, int ldb, int kiters,
                                        bf16* As, bf16* Bs, f32x4 acc[4][4]) {
    const int tid  = threadIdx.x;
    const int wave = tid >> 6;
    const int lane = tid & 63;

    const int F0 = wave * 2048 + lane * 16;  // byte offset; 4 waves cover 8KB
    const int F1 = F0 + 1024;
    const int r0 = F0 >> 6, c0 = (F0 & 63) >> 1;  // 64B (=32 bf16) per row
    const int r1 = F1 >> 6, c1 = (F1 & 63) >> 1;
    const bf16* ga0 = Ablk + (size_t)r0 * lda + c0;
    const bf16* ga1 = Ablk + (size_t)r1 * lda + c1;
    const bf16* gb0 = Bblk + (size_t)r0 * ldb + c0;
    const bf16* gb1 = Bblk + (size_t)r1 * ldb + c1;
    bf16* lA0 = (bf16*)((char*)As + F0);
    bf16* lA1 = (bf16*)((char*)As + F1);
    bf16* lB0 = (bf16*)((char*)Bs + F0);
    bf16* lB1 = (bf16*)((char*)Bs + F1);

    const int waveM = wave >> 1, waveN = wave & 1;
    const int mrow = waveM * 64 + (lane & 15);
    const int nrow = waveN * 64 + (lane & 15);
    const int koff = (lane >> 4) * 8;

    for (int it = 0; it < kiters; ++it) {
        gload_lds16(ga0, lA0);
        gload_lds16(ga1, lA1);
        gload_lds16(gb0, lB0);
        gload_lds16(gb1, lB1);
        ga0 += BK; ga1 += BK; gb0 += BK; gb1 += BK;
        __syncthreads();

        bf16x8 af[4], bfr[4];
#pragma unroll
        for (int mi = 0; mi < 4; ++mi)
            af[mi] = *(const bf16x8*)(As + (mrow + mi * 16) * BK + koff);
#pragma unroll
        for (int ni = 0; ni < 4; ++ni)
            bfr[ni] = *(const bf16x8*)(Bs + (nrow + ni * 16) * BK + koff);
#pragma unroll
        for (int mi = 0; mi < 4; ++mi)
#pragma unroll
            for (int ni = 0; ni < 4; ++ni)
                acc[mi][ni] = __builtin_amdgcn_mfma_f32_16x16x32_bf16(
                    af[mi], bfr[ni], acc[mi][ni], 0, 0, 0);
        __syncthreads();
    }
}

// ---------------- plain GEMM: C[m][n] = A*BT^T, bf16 store -----------------
__global__ __launch_bounds__(256, 2) void k_gemm_plain(
    const bf16* __restrict__ A, long long aBatch,
    const bf16* __restrict__ BT, long long bBatch,
    bf16* __restrict__ C, long long cBatch,
    int lda, int ldb, int ldc, int kiters) {
    __shared__ __align__(16) bf16 As[128 * BK];
    __shared__ __align__(16) bf16 Bs[128 * BK];
    const int nBase = blockIdx.x * 128;
    const int mBase = blockIdx.y * 128;
    const int z = blockIdx.z;
    const bf16* Ab = A + (size_t)z * aBatch + (size_t)mBase * lda;
    const bf16* Bb = BT + (size_t)z * bBatch + (size_t)nBase * ldb;

    f32x4 acc[4][4];
    zero_acc(acc);
    mm_tile(Ab, Bb, lda, ldb, kiters, As, Bs, acc);

    const int tid = threadIdx.x, wave = tid >> 6, lane = tid & 63;
    const int waveM = wave >> 1, waveN = wave & 1;
    const int quad = lane >> 4, cno = lane & 15;
    bf16* Cb = C + (size_t)z * cBatch;
#pragma unroll
    for (int mi = 0; mi < 4; ++mi) {
        int row0 = mBase + waveM * 64 + mi * 16 + quad * 4;
#pragma unroll
        for (int ni = 0; ni < 4; ++ni) {
            int col = nBase + waveN * 64 + ni * 16 + cno;
#pragma unroll
            for (int r = 0; r < 4; ++r)
                Cb[(size_t)(row0 + r) * ldc + col] = __float2bfloat16(acc[mi][ni][r]);
        }
    }
}

// ---------------- score: packed P~ = exp(mask(Q K^T / 16)) -----------------
// Only the 528 lower-tri tiles per batch are launched; flat index f decodes
// to (qt, kt). P packed per batch: block-row qt starts at element
// 16384*qt*(qt+1)/2, rows have pitch (qt+1)*128. Row sums -> lsum atomics.
#define P_BATCH 8650752ll  // 528 * 16384 elements per batch
__global__ __launch_bounds__(256, 2) void k_score(
    const bf16* __restrict__ Qm, const bf16* __restrict__ Km,
    bf16* __restrict__ P, float* __restrict__ lsum) {
    const int f = blockIdx.x, b = blockIdx.z;
    // decode f -> (qt, kt): qt = floor((sqrt(8f+1)-1)/2), kt = f - tri(qt)
    int qt = (int)((sqrtf(8.f * (float)f + 1.f) - 1.f) * 0.5f);
    while ((qt + 1) * (qt + 2) / 2 <= f) ++qt;
    while (qt * (qt + 1) / 2 > f) --qt;
    const int kt = f - qt * (qt + 1) / 2;

    __shared__ __align__(16) bf16 As[128 * BK];
    __shared__ __align__(16) bf16 Bs[128 * BK];

    const bf16* Ab = Qm + ((size_t)b * 4096 + (size_t)qt * 128) * 256;
    const bf16* Bb = Km + ((size_t)b * 4096 + (size_t)kt * 128) * 256;

    f32x4 acc[4][4];
    zero_acc(acc);
    mm_tile(Ab, Bb, 256, 256, 256 / BK, As, Bs, acc);

    const int tid = threadIdx.x, wave = tid >> 6, lane = tid & 63;
    const int waveM = wave >> 1, waveN = wave & 1;
    const int quad = lane >> 4, cno = lane & 15;
    const int pitch = (qt + 1) * 128;
    bf16* Pb = P + b * P_BATCH + (size_t)16384 * (qt * (qt + 1) / 2);
    float* lb = lsum + b * 4096;
#pragma unroll
    for (int mi = 0; mi < 4; ++mi) {
        const int lq0 = waveM * 64 + mi * 16 + quad * 4;
        float rs[4] = {0.f, 0.f, 0.f, 0.f};
#pragma unroll
        for (int ni = 0; ni < 4; ++ni) {
            const int cn = waveN * 64 + ni * 16 + cno;
            const int gk = kt * 128 + cn;
#pragma unroll
            for (int r = 0; r < 4; ++r) {
                const int gq = qt * 128 + lq0 + r;
                float s = acc[mi][ni][r] * 0.0625f;  // 1/sqrt(256)
                // ref quirk: masked OR exactly-zero score -> exp = 0
                float p = (gk <= gq && s != 0.0f) ? __expf(s) : 0.0f;
                bf16 pb = __float2bfloat16(p);
                Pb[(size_t)(lq0 + r) * pitch + gk] = pb;
                rs[r] += __bfloat162float(pb);  // sum what PV multiplies
            }
        }
#pragma unroll
        for (int r = 0; r < 4; ++r) {
            float v = rs[r];
            v += __shfl_xor(v, 1);
            v += __shfl_xor(v, 2);
            v += __shfl_xor(v, 4);
            v += __shfl_xor(v, 8);
            if (cno == 0) atomicAdd(&lb[qt * 128 + lq0 + r], v);
        }
    }
}

// --------------- PV GEMM, split-k uniform chunks -----------------------
// blockIdx.x = chunk id f in [0,80) decoding to (qt, kc): qt has
// floor(qt/8)+1 chunks of up to 8 k-tiles (32 k-steps) each. 2560 blocks,
// 8 resident/CU; makespan floor = 32 k-steps (was 128). Partial [128x128]
// tiles scaled by 1/l (linear => exact) then combined: plain store when the
// tile has one chunk (qt<=7), else global_atomic_add_f32 into zeroed Out.
__global__ __launch_bounds__(256, 2) void k_pv(
    const bf16* __restrict__ P, const bf16* __restrict__ VT,
    const float* __restrict__ lsum, float* __restrict__ Out) {
    __shared__ __align__(16) bf16 As[128 * BK];
    __shared__ __align__(16) bf16 Bs[128 * BK];
    // decode chunk: qt consumes (qt>>3)+1 chunk slots
    int qt = 0, rem = blockIdx.x;
    while (rem >= (qt >> 3) + 1) { rem -= (qt >> 3) + 1; ++qt; }
    const int kc = rem;
    const int nchunks = (qt >> 3) + 1;
    const int ktiles = (kc == nchunks - 1) ? (qt + 1 - kc * 8) : 8;
    const int dvBase = blockIdx.y * 128;
    const int b = blockIdx.z;
    const int tid = threadIdx.x, wave = tid >> 6, lane = tid & 63;
    const int waveM = wave >> 1, waveN = wave & 1;
    const int quad = lane >> 4, cno = lane & 15;

    const int pitch = (qt + 1) * 128;
    const bf16* Ab = P + b * P_BATCH + (size_t)16384 * (qt * (qt + 1) / 2)
                     + kc * 1024;
    const bf16* Bb = VT + ((size_t)b * 1024 + dvBase) * 4096 + kc * 1024;
    float* Ob = Out + (size_t)b * 4096 * 1024;
    const float* lb = lsum + b * 4096;

    f32x4 acc[4][4];
    zero_acc(acc);
    mm_tile(Ab, Bb, pitch, 4096, ktiles * 4, As, Bs, acc);

#pragma unroll
    for (int mi = 0; mi < 4; ++mi) {
        const int lq0 = waveM * 64 + mi * 16 + quad * 4;
#pragma unroll
        for (int r = 0; r < 4; ++r) {
            const int gq = qt * 128 + lq0 + r;
            const float inv = 1.0f / lb[gq];
#pragma unroll
            for (int ni = 0; ni < 4; ++ni) {
                const int col = dvBase + waveN * 64 + ni * 16 + cno;
                float v = acc[mi][ni][r] * inv;
                if (nchunks == 1)
                    Ob[(size_t)gq * 1024 + col] = v;
                else
                    unsafeAtomicAdd(&Ob[(size_t)gq * 1024 + col], v);
            }
        }
    }
}

// ----------------------------- prep kernels (f32 inputs) -------------------
__global__ void k_cast(const float4* __restrict__ in, bf16* __restrict__ out,
                       int n4) {
    int i = blockIdx.x * 256 + threadIdx.x;
    if (i >= n4) return;
    float4 v = in[i];
    bf16x4 o;
    o[0] = (__bf16)v.x; o[1] = (__bf16)v.y; o[2] = (__bf16)v.z; o[3] = (__bf16)v.w;
    *(bf16x4*)(out + 4 * (size_t)i) = o;
}

// out[idx] = in[(idx & mask) * tstride + (idx >> shift)]; n = total elements.
__global__ void k_transpose(const float* __restrict__ in, bf16* __restrict__ out,
                            int n, int mask, int shift, int tstride) {
    int idx = blockIdx.x * 256 + threadIdx.x;
    if (idx >= n) return;
    out[idx] = __float2bfloat16(in[(size_t)(idx & mask) * tstride + (idx >> shift)]);
}

extern "C" void kernel_launch(void* const* d_in, const int* in_sizes, int n_in,
                              void* d_out, int out_size, void* d_ws, size_t ws_size,
                              hipStream_t stream) {
    const int B = 4, N = 4096, E = 1024, D = 256;
    const float* X   = (const float*)d_in[0];  // [4,4096,1024]
    const float* Wq  = (const float*)d_in[1];  // [1024,256]
    const float* Wk  = (const float*)d_in[2];  // [1024,256]
    const float* Wvd = (const float*)d_in[3];  // [1024,256]
    const float* Wvu = (const float*)d_in[4];  // [256,1024]
    float* out = (float*)d_out;                // [4,4096,1024]

    // ---- workspace layout (122 MiB + 64 KiB; P overlays dead Xb/weights) ---
    const long long MiB = 1ll << 20;
    char* ws = (char*)d_ws;
    bf16* Xb     = (bf16*)(ws);                       // [ 0,32)  [16384][1024]
    bf16* WqT    = (bf16*)(ws + 32 * MiB);            // 512 KiB  [256][1024]
    bf16* WkT    = (bf16*)(ws + 32 * MiB + 524288);   // 512 KiB (contiguous!)
    bf16* WvdT   = (bf16*)(ws + 32 * MiB + 1048576);  // 512 KiB (contiguous!)
    bf16* WvupT  = (bf16*)(ws + 32 * MiB + 1572864);  // 512 KiB  [1024][256]
    bf16* P      = (bf16*)(ws);                       // [ 0,66)  packed tri
    bf16* Qm     = (bf16*)(ws + 66 * MiB);            // [66,74)  [16384][256]
    bf16* Km     = (bf16*)(ws + 74 * MiB);            // [74,82)  = Qm+cBatch
    bf16* Vd     = (bf16*)(ws + 82 * MiB);            // [82,90)  = Qm+2*cBatch
    bf16* VT     = (bf16*)(ws + 90 * MiB);            // [90,122) [4][1024][4096]
    float* lsum  = (float*)(ws + 122 * MiB);          // 64 KiB   [4][4096]
    // lifetime: Xb/W*T dead before k_score writes P (alias [0,66) ok)

    // zero Out (split-k chunks atomicAdd into it) and lsum up front
    hipMemsetAsync(out, 0, (size_t)B * N * E * sizeof(float), stream);
    hipMemsetAsync(lsum, 0, (size_t)B * N * sizeof(float), stream);

    const int n4 = B * N * E / 4;
    k_cast<<<(n4 + 255) / 256, 256, 0, stream>>>((const float4*)X, Xb, n4);
    // WqT[d][e] = Wq[e][d]: idx=d*1024+e -> e=idx&1023, d=idx>>10, stride 256
    k_transpose<<<1024, 256, 0, stream>>>(Wq,  WqT,  E * D, 1023, 10, 256);
    k_transpose<<<1024, 256, 0, stream>>>(Wk,  WkT,  E * D, 1023, 10, 256);
    k_transpose<<<1024, 256, 0, stream>>>(Wvd, WvdT, E * D, 1023, 10, 256);
    // WvupT[dv][d] = Wvu[d][dv]: idx=dv*256+d -> d=idx&255, dv=idx>>8, str 1024
    k_transpose<<<1024, 256, 0, stream>>>(Wvu, WvupT, D * E, 255, 8, 1024);

    // Q,K,Vd = Xb @ {Wq,Wk,Wvdown}  (z=3: outputs at Qm + z*8MiB)
    k_gemm_plain<<<dim3(D / 128, (B * N) / 128, 3), 256, 0, stream>>>(
        Xb, 0, WqT, (long long)D * E, Qm, (long long)B * N * D,
        E, E, D, E / BK);

    // VT[b][dv][n] = sum_d WvupT[dv][d] * Vd[b][n][d]   (K=256)
    k_gemm_plain<<<dim3(N / 128, E / 128, B), 256, 0, stream>>>(
        WvupT, 0, Vd, (long long)N * D, VT, (long long)E * N,
        D, D, N, D / BK);

    // P~ = exp(mask(Q K^T / 16)) packed; row sums -> lsum (528 tri tiles/b)
    k_score<<<dim3(528, 1, B), 256, 0, stream>>>(Qm, Km, P, lsum);

    // Out = (P~ @ V) / l  (split-k: 80 uniform chunks per (dv,b))
    k_pv<<<dim3(80, 8, 4), 256, 0, stream>>>(P, VT, lsum, out);
}

// Round 4
// 331.563 us; speedup vs baseline: 1.2252x; 1.2252x over previous
//
#include <hip/hip_runtime.h>
#include <hip/hip_bf16.h>

// DotProductAttention: B=4, N=4096, E=1024, D=256. f32 in/out.
// Pipeline: cast/prep -> QKV GEMM (z=3) -> VT GEMM -> k_score (packed
// lower-tri P~, rowsum l) -> k_pv (O = P~ @ V / l).
// R7: k_score enumerates only the 528 lower-tri tiles/b.
// R8/R9: coset-balanced k_pv (1024 blocks): MfmaUtil stuck 24% (residency
// reg-capped at 4 blocks/CU; makespan = longest serial chain).
// R10 FAILED: split-k atomics -> WRITE 3x, BW fell to 1.9TB/s. Reverted.
// R11: (a) XCD-grouped k_pv decode: dv outer (l>>7) so the 8 dv-siblings
// sharing a (qt,b) P-tile satisfy l%8==const -> same XCD -> P fetched once
// (FETCH was 310MB vs 101MB ideal). qt from (x=l%8, m=(k+dv/2)&3) via
// {x,15-x,16+x,31-x}: co-resident CU cosets sum qt=62 -> 264 k-steps/CU.
// (b) double-buffered LDS staging with counted vmcnt(4) + raw s_barrier
// (no __syncthreads vmcnt(0) drain): hides ~900cy HBM latency of the cold
// P stream under MFMA of the previous k-step. Applied to all MFMA kernels.

typedef __hip_bfloat16 bf16;
typedef __bf16 bf16x4 __attribute__((ext_vector_type(4)));
typedef __bf16 bf16x8 __attribute__((ext_vector_type(8)));
typedef float f32x4 __attribute__((ext_vector_type(4)));

#define BK 32
#define HALF_BYTES 8192  // 128*BK*2 bytes per LDS buffer half

__device__ __forceinline__ void gload_lds16(const bf16* g, bf16* l) {
    __builtin_amdgcn_global_load_lds(
        (const __attribute__((address_space(1))) unsigned int*)g,
        (__attribute__((address_space(3))) unsigned int*)l, 16, 0, 0);
}

__device__ __forceinline__ void zero_acc(f32x4 acc[4][4]) {
#pragma unroll
    for (int mi = 0; mi < 4; ++mi)
#pragma unroll
        for (int ni = 0; ni < 4; ++ni) {
            f32x4 zf = {0.f, 0.f, 0.f, 0.f};
            acc[mi][ni] = zf;
        }
}

// One k-step compute: ds_read fragments from buffer `cur`, 16 MFMA.
__device__ __forceinline__ void compute_step(const bf16* As, const bf16* Bs,
                                             int cur, int mrow, int nrow,
                                             int koff, f32x4 acc[4][4]) {
    const bf16* Ar = (const bf16*)((const char*)As + cur * HALF_BYTES);
    const bf16* Br = (const bf16*)((const char*)Bs + cur * HALF_BYTES);
    bf16x8 af[4], bfr[4];
#pragma unroll
    for (int mi = 0; mi < 4; ++mi)
        af[mi] = *(const bf16x8*)(Ar + (mrow + mi * 16) * BK + koff);
#pragma unroll
    for (int ni = 0; ni < 4; ++ni)
        bfr[ni] = *(const bf16x8*)(Br + (nrow + ni * 16) * BK + koff);
#pragma unroll
    for (int mi = 0; mi < 4; ++mi)
#pragma unroll
        for (int ni = 0; ni < 4; ++ni)
            acc[mi][ni] = __builtin_amdgcn_mfma_f32_16x16x32_bf16(
                af[mi], bfr[ni], acc[mi][ni], 0, 0, 0);
}

// C-tile accumulate: acc += A[128 x K] * BT[128 x K]^T.
// Double-buffered: stage k+1 while computing k; counted vmcnt(4) so the
// prefetch stays in flight across the barrier (never drains to 0 mid-loop).
__device__ __forceinline__ void mm_tile(const bf16* __restrict__ Ablk,
                                        const bf16* __restrict__ Bblk,
                                        int lda, int ldb, int kiters,
                                        bf16* As, bf16* Bs, f32x4 acc[4][4]) {
    const int tid  = threadIdx.x;
    const int wave = tid >> 6;
    const int lane = tid & 63;

    const int F0 = wave * 2048 + lane * 16;  // byte offset; 4 waves cover 8KB
    const int F1 = F0 + 1024;
    const int r0 = F0 >> 6, c0 = (F0 & 63) >> 1;  // 64B (=32 bf16) per row
    const int r1 = F1 >> 6, c1 = (F1 & 63) >> 1;
    const bf16* ga0 = Ablk + (size_t)r0 * lda + c0;
    const bf16* ga1 = Ablk + (size_t)r1 * lda + c1;
    const bf16* gb0 = Bblk + (size_t)r0 * ldb + c0;
    const bf16* gb1 = Bblk + (size_t)r1 * ldb + c1;

    const int waveM = wave >> 1, waveN = wave & 1;
    const int mrow = waveM * 64 + (lane & 15);
    const int nrow = waveN * 64 + (lane & 15);
    const int koff = (lane >> 4) * 8;

    // prologue: stage tile 0 -> buf 0
    gload_lds16(ga0, (bf16*)((char*)As + F0));
    gload_lds16(ga1, (bf16*)((char*)As + F1));
    gload_lds16(gb0, (bf16*)((char*)Bs + F0));
    gload_lds16(gb1, (bf16*)((char*)Bs + F1));
    ga0 += BK; ga1 += BK; gb0 += BK; gb1 += BK;

    int cur = 0;
    for (int it = 0; it < kiters - 1; ++it) {
        const int nxt = cur ^ 1;
        // stage tile it+1 -> buf nxt (4 loads; outstanding rises to 8)
        char* Ad = (char*)As + nxt * HALF_BYTES;
        char* Bd = (char*)Bs + nxt * HALF_BYTES;
        gload_lds16(ga0, (bf16*)(Ad + F0));
        gload_lds16(ga1, (bf16*)(Ad + F1));
        gload_lds16(gb0, (bf16*)(Bd + F0));
        gload_lds16(gb1, (bf16*)(Bd + F1));
        ga0 += BK; ga1 += BK; gb0 += BK; gb1 += BK;

        // wait for buf cur's 4 loads (oldest); keep nxt's 4 in flight
        __builtin_amdgcn_sched_barrier(0);
        asm volatile("s_waitcnt vmcnt(4)" ::: "memory");
        __builtin_amdgcn_sched_barrier(0);
        __builtin_amdgcn_s_barrier();
        __builtin_amdgcn_sched_barrier(0);

        compute_step(As, Bs, cur, mrow, nrow, koff, acc);

        // drain own ds_reads, then barrier: next iter overwrites buf cur
        __builtin_amdgcn_sched_barrier(0);
        asm volatile("s_waitcnt lgkmcnt(0)" ::: "memory");
        __builtin_amdgcn_sched_barrier(0);
        __builtin_amdgcn_s_barrier();
        __builtin_amdgcn_sched_barrier(0);
        cur = nxt;
    }

    // epilogue: last tile (no prefetch outstanding afterwards)
    __builtin_amdgcn_sched_barrier(0);
    asm volatile("s_waitcnt vmcnt(0)" ::: "memory");
    __builtin_amdgcn_sched_barrier(0);
    __builtin_amdgcn_s_barrier();
    __builtin_amdgcn_sched_barrier(0);
    compute_step(As, Bs, cur, mrow, nrow, koff, acc);
}

// ---------------- plain GEMM: C[m][n] = A*BT^T, bf16 store -----------------
__global__ __launch_bounds__(256, 2) void k_gemm_plain(
    const bf16* __restrict__ A, long long aBatch,
    const bf16* __restrict__ BT, long long bBatch,
    bf16* __restrict__ C, long long cBatch,
    int lda, int ldb, int ldc, int kiters) {
    __shared__ __align__(16) bf16 As[2 * 128 * BK];
    __shared__ __align__(16) bf16 Bs[2 * 128 * BK];
    const int nBase = blockIdx.x * 128;
    const int mBase = blockIdx.y * 128;
    const int z = blockIdx.z;
    const bf16* Ab = A + (size_t)z * aBatch + (size_t)mBase * lda;
    const bf16* Bb = BT + (size_t)z * bBatch + (size_t)nBase * ldb;

    f32x4 acc[4][4];
    zero_acc(acc);
    mm_tile(Ab, Bb, lda, ldb, kiters, As, Bs, acc);

    const int tid = threadIdx.x, wave = tid >> 6, lane = tid & 63;
    const int waveM = wave >> 1, waveN = wave & 1;
    const int quad = lane >> 4, cno = lane & 15;
    bf16* Cb = C + (size_t)z * cBatch;
#pragma unroll
    for (int mi = 0; mi < 4; ++mi) {
        int row0 = mBase + waveM * 64 + mi * 16 + quad * 4;
#pragma unroll
        for (int ni = 0; ni < 4; ++ni) {
            int col = nBase + waveN * 64 + ni * 16 + cno;
#pragma unroll
            for (int r = 0; r < 4; ++r)
                Cb[(size_t)(row0 + r) * ldc + col] = __float2bfloat16(acc[mi][ni][r]);
        }
    }
}

// ---------------- score: packed P~ = exp(mask(Q K^T / 16)) -----------------
// Only the 528 lower-tri tiles per batch are launched; flat index f decodes
// to (qt, kt). P packed per batch: block-row qt starts at element
// 16384*qt*(qt+1)/2, rows have pitch (qt+1)*128. Row sums -> lsum atomics.
#define P_BATCH 8650752ll  // 528 * 16384 elements per batch
__global__ __launch_bounds__(256, 2) void k_score(
    const bf16* __restrict__ Qm, const bf16* __restrict__ Km,
    bf16* __restrict__ P, float* __restrict__ lsum) {
    const int f = blockIdx.x, b = blockIdx.z;
    // decode f -> (qt, kt): qt = floor((sqrt(8f+1)-1)/2), kt = f - tri(qt)
    int qt = (int)((sqrtf(8.f * (float)f + 1.f) - 1.f) * 0.5f);
    while ((qt + 1) * (qt + 2) / 2 <= f) ++qt;
    while (qt * (qt + 1) / 2 > f) --qt;
    const int kt = f - qt * (qt + 1) / 2;

    __shared__ __align__(16) bf16 As[2 * 128 * BK];
    __shared__ __align__(16) bf16 Bs[2 * 128 * BK];

    const bf16* Ab = Qm + ((size_t)b * 4096 + (size_t)qt * 128) * 256;
    const bf16* Bb = Km + ((size_t)b * 4096 + (size_t)kt * 128) * 256;

    f32x4 acc[4][4];
    zero_acc(acc);
    mm_tile(Ab, Bb, 256, 256, 256 / BK, As, Bs, acc);

    const int tid = threadIdx.x, wave = tid >> 6, lane = tid & 63;
    const int waveM = wave >> 1, waveN = wave & 1;
    const int quad = lane >> 4, cno = lane & 15;
    const int pitch = (qt + 1) * 128;
    bf16* Pb = P + b * P_BATCH + (size_t)16384 * (qt * (qt + 1) / 2);
    float* lb = lsum + b * 4096;
#pragma unroll
    for (int mi = 0; mi < 4; ++mi) {
        const int lq0 = waveM * 64 + mi * 16 + quad * 4;
        float rs[4] = {0.f, 0.f, 0.f, 0.f};
#pragma unroll
        for (int ni = 0; ni < 4; ++ni) {
            const int cn = waveN * 64 + ni * 16 + cno;
            const int gk = kt * 128 + cn;
#pragma unroll
            for (int r = 0; r < 4; ++r) {
                const int gq = qt * 128 + lq0 + r;
                float s = acc[mi][ni][r] * 0.0625f;  // 1/sqrt(256)
                // ref quirk: masked OR exactly-zero score -> exp = 0
                float p = (gk <= gq && s != 0.0f) ? __expf(s) : 0.0f;
                bf16 pb = __float2bfloat16(p);
                Pb[(size_t)(lq0 + r) * pitch + gk] = pb;
                rs[r] += __bfloat162float(pb);  // sum what PV multiplies
            }
        }
#pragma unroll
        for (int r = 0; r < 4; ++r) {
            float v = rs[r];
            v += __shfl_xor(v, 1);
            v += __shfl_xor(v, 2);
            v += __shfl_xor(v, 4);
            v += __shfl_xor(v, 8);
            if (cno == 0) atomicAdd(&lb[qt * 128 + lq0 + r], v);
        }
    }
}

// --------------- PV GEMM, XCD-grouped + CU-coset balanced ------------------
// l = dv*128 + (b*32 + u): the 8 dv-siblings of a (qt,b) share l%8 -> same
// XCD under round-robin dispatch -> their shared P-tile is fetched once per
// XCD L2, not 8x. qt from x=u&7, slot m=((u>>3)+(dv>>1))&3 via
// {x, 15-x, 16+x, 31-x}: the 4 co-resident blocks per CU (blockIdx spaced
// 256) get qts summing to 62 -> every CU carries exactly 264 k-steps, and
// long chains overlap short ones on the same CU.
__global__ __launch_bounds__(256, 2) void k_pv(
    const bf16* __restrict__ P, const bf16* __restrict__ VT,
    const float* __restrict__ lsum, float* __restrict__ Out) {
    __shared__ __align__(16) bf16 As[2 * 128 * BK];
    __shared__ __align__(16) bf16 Bs[2 * 128 * BK];
    const int l = blockIdx.x;        // 0..1023
    const int dv = l >> 7;           // 0..7 (outer -> XCD-invariant)
    const int w = l & 127;
    const int b = w >> 5;            // 0..3
    const int u = w & 31;            // 0..31
    const int x = u & 7;             // XCD slot (= l%8)
    const int k = u >> 3;            // 0..3
    const int m = (k + (dv >> 1)) & 3;
    const int qt = (m == 0) ? x : (m == 1) ? (15 - x)
                 : (m == 2) ? (16 + x) : (31 - x);
    const int dvBase = dv * 128;
    const int tid = threadIdx.x, wave = tid >> 6, lane = tid & 63;
    const int waveM = wave >> 1, waveN = wave & 1;
    const int quad = lane >> 4, cno = lane & 15;

    const bf16* Bb = VT + ((size_t)b * 1024 + dvBase) * 4096;
    float* Ob = Out + (size_t)b * 4096 * 1024;
    const float* lb = lsum + b * 4096;

    const int pitch = (qt + 1) * 128;
    const bf16* Ab = P + b * P_BATCH + (size_t)16384 * (qt * (qt + 1) / 2);

    f32x4 acc[4][4];
    zero_acc(acc);
    mm_tile(Ab, Bb, pitch, 4096, (qt + 1) * (128 / BK), As, Bs, acc);

#pragma unroll
    for (int mi = 0; mi < 4; ++mi) {
        const int lq0 = waveM * 64 + mi * 16 + quad * 4;
#pragma unroll
        for (int r = 0; r < 4; ++r) {
            const int gq = qt * 128 + lq0 + r;
            const float inv = 1.0f / lb[gq];
#pragma unroll
            for (int ni = 0; ni < 4; ++ni) {
                const int col = dvBase + waveN * 64 + ni * 16 + cno;
                Ob[(size_t)gq * 1024 + col] = acc[mi][ni][r] * inv;
            }
        }
    }
}

// ----------------------------- prep kernels (f32 inputs) -------------------
__global__ void k_cast(const float4* __restrict__ in, bf16* __restrict__ out,
                       int n4) {
    int i = blockIdx.x * 256 + threadIdx.x;
    if (i >= n4) return;
    float4 v = in[i];
    bf16x4 o;
    o[0] = (__bf16)v.x; o[1] = (__bf16)v.y; o[2] = (__bf16)v.z; o[3] = (__bf16)v.w;
    *(bf16x4*)(out + 4 * (size_t)i) = o;
}

// out[idx] = in[(idx & mask) * tstride + (idx >> shift)]; n = total elements.
__global__ void k_transpose(const float* __restrict__ in, bf16* __restrict__ out,
                            int n, int mask, int shift, int tstride) {
    int idx = blockIdx.x * 256 + threadIdx.x;
    if (idx >= n) return;
    out[idx] = __float2bfloat16(in[(size_t)(idx & mask) * tstride + (idx >> shift)]);
}

extern "C" void kernel_launch(void* const* d_in, const int* in_sizes, int n_in,
                              void* d_out, int out_size, void* d_ws, size_t ws_size,
                              hipStream_t stream) {
    const int B = 4, N = 4096, E = 1024, D = 256;
    const float* X   = (const float*)d_in[0];  // [4,4096,1024]
    const float* Wq  = (const float*)d_in[1];  // [1024,256]
    const float* Wk  = (const float*)d_in[2];  // [1024,256]
    const float* Wvd = (const float*)d_in[3];  // [1024,256]
    const float* Wvu = (const float*)d_in[4];  // [256,1024]
    float* out = (float*)d_out;                // [4,4096,1024]

    // ---- workspace layout (122 MiB + 64 KiB; P overlays dead Xb/weights) ---
    const long long MiB = 1ll << 20;
    char* ws = (char*)d_ws;
    bf16* Xb     = (bf16*)(ws);                       // [ 0,32)  [16384][1024]
    bf16* WqT    = (bf16*)(ws + 32 * MiB);            // 512 KiB  [256][1024]
    bf16* WkT    = (bf16*)(ws + 32 * MiB + 524288);   // 512 KiB (contiguous!)
    bf16* WvdT   = (bf16*)(ws + 32 * MiB + 1048576);  // 512 KiB (contiguous!)
    bf16* WvupT  = (bf16*)(ws + 32 * MiB + 1572864);  // 512 KiB  [1024][256]
    bf16* P      = (bf16*)(ws);                       // [ 0,66)  packed tri
    bf16* Qm     = (bf16*)(ws + 66 * MiB);            // [66,74)  [16384][256]
    bf16* Km     = (bf16*)(ws + 74 * MiB);            // [74,82)  = Qm+cBatch
    bf16* Vd     = (bf16*)(ws + 82 * MiB);            // [82,90)  = Qm+2*cBatch
    bf16* VT     = (bf16*)(ws + 90 * MiB);            // [90,122) [4][1024][4096]
    float* lsum  = (float*)(ws + 122 * MiB);          // 64 KiB   [4][4096]
    // lifetime: Xb/W*T dead before k_score writes P (alias [0,66) ok)

    const int n4 = B * N * E / 4;
    k_cast<<<(n4 + 255) / 256, 256, 0, stream>>>((const float4*)X, Xb, n4);
    // WqT[d][e] = Wq[e][d]: idx=d*1024+e -> e=idx&1023, d=idx>>10, stride 256
    k_transpose<<<1024, 256, 0, stream>>>(Wq,  WqT,  E * D, 1023, 10, 256);
    k_transpose<<<1024, 256, 0, stream>>>(Wk,  WkT,  E * D, 1023, 10, 256);
    k_transpose<<<1024, 256, 0, stream>>>(Wvd, WvdT, E * D, 1023, 10, 256);
    // WvupT[dv][d] = Wvu[d][dv]: idx=dv*256+d -> d=idx&255, dv=idx>>8, str 1024
    k_transpose<<<1024, 256, 0, stream>>>(Wvu, WvupT, D * E, 255, 8, 1024);
    hipMemsetAsync(lsum, 0, (size_t)B * N * sizeof(float), stream);

    // Q,K,Vd = Xb @ {Wq,Wk,Wvdown}  (z=3: outputs at Qm + z*8MiB)
    k_gemm_plain<<<dim3(D / 128, (B * N) / 128, 3), 256, 0, stream>>>(
        Xb, 0, WqT, (long long)D * E, Qm, (long long)B * N * D,
        E, E, D, E / BK);

    // VT[b][dv][n] = sum_d WvupT[dv][d] * Vd[b][n][d]   (K=256)
    k_gemm_plain<<<dim3(N / 128, E / 128, B), 256, 0, stream>>>(
        WvupT, 0, Vd, (long long)N * D, VT, (long long)E * N,
        D, D, N, D / BK);

    // P~ = exp(mask(Q K^T / 16)) packed; row sums -> lsum (528 tri tiles/b)
    k_score<<<dim3(528, 1, B), 256, 0, stream>>>(Qm, Km, P, lsum);

    // Out = (P~ @ V) / l  (XCD-grouped, CU-coset balanced: 264 k-steps/CU)
    k_pv<<<dim3(1024, 1, 1), 256, 0, stream>>>(P, VT, lsum, out);
}